// Round 1
// baseline (196.904 us; speedup 1.0000x reference)
//
#include <hip/hip_runtime.h>
#include <hip/hip_bf16.h>

#define N_NODES 20000
#define BATCH   4
#define F_DIM   256
#define O_DIM   256
#define E_EDGES 160000
#define M_ROWS  (BATCH * N_NODES)   // 80000
#define K_DIM   512                 // concat: X (0..255) | Xagg (256..511)

typedef __bf16 bf16_t;
typedef bf16_t bf16x8 __attribute__((ext_vector_type(8)));
typedef bf16_t bf16x4 __attribute__((ext_vector_type(4)));
typedef float  f32x4  __attribute__((ext_vector_type(4)));

// ---------- X fp32 -> bf16 into A-buffer cols 0..255 ----------
__global__ void __launch_bounds__(256) k_convert_x(const float* __restrict__ X,
                                                   bf16_t* __restrict__ A) {
    int t = blockIdx.x * 256 + threadIdx.x;   // 5.12M threads, 4 floats each
    int m = t >> 6;
    int c = (t & 63) << 2;
    const float4 v = *reinterpret_cast<const float4*>(X + (size_t)m * F_DIM + c);
    bf16x4 o = { (bf16_t)v.x, (bf16_t)v.y, (bf16_t)v.z, (bf16_t)v.w };
    *reinterpret_cast<bf16x4*>(A + (size_t)m * K_DIM + c) = o;
}

// ---------- weights: Wt[o][k] = (k<256 ? W1[k][o] : W2[k-256][o]) as bf16 ----------
__global__ void k_wt(const float* __restrict__ W1, const float* __restrict__ W2,
                     bf16_t* __restrict__ Wt) {
    int k = blockIdx.x;        // 0..511
    int o = threadIdx.x;       // 0..255
    float v = (k < F_DIM) ? W1[(size_t)k * O_DIM + o] : W2[(size_t)(k - F_DIM) * O_DIM + o];
    Wt[(size_t)o * K_DIM + k] = (bf16_t)v;
}

// ---------- CSR build ----------
__global__ void k_deg(const int* __restrict__ rows, int* __restrict__ deg) {
    int e = blockIdx.x * 256 + threadIdx.x;   // grid sized exactly E
    atomicAdd(&deg[rows[e]], 1);
}

__global__ void k_scan(const int* __restrict__ deg, int* __restrict__ offsets,
                       int* __restrict__ cursor) {
    __shared__ int sums[256];
    const int T = 256;
    int t = threadIdx.x;
    int chunk = (N_NODES + T - 1) / T;        // 79
    int begin = t * chunk; if (begin > N_NODES) begin = N_NODES;
    int end = begin + chunk; if (end > N_NODES) end = N_NODES;
    int s = 0;
    for (int i = begin; i < end; ++i) s += deg[i];
    sums[t] = s;
    __syncthreads();
    if (t == 0) {
        int run = 0;
        for (int i = 0; i < T; ++i) { int v = sums[i]; sums[i] = run; run += v; }
        offsets[N_NODES] = run;   // == E
    }
    __syncthreads();
    int run = sums[t];
    for (int i = begin; i < end; ++i) {
        offsets[i] = run; cursor[i] = run;
        run += deg[i];
    }
}

__global__ void k_scatter(const int* __restrict__ rows, const int* __restrict__ cols,
                          const float* __restrict__ vals, int* __restrict__ cursor,
                          int* __restrict__ ccol, float* __restrict__ cval) {
    int e = blockIdx.x * 256 + threadIdx.x;
    int r = rows[e];
    int p = atomicAdd(&cursor[r], 1);
    ccol[p] = cols[e];
    cval[p] = vals[e];
}

// ---------- SpMM: Xagg[b,n,:] = sum_e vals[e]*X[b,cols[e],:]  (bf16 in, fp32 acc, bf16 out) ----------
__global__ void __launch_bounds__(256) k_spmm(const bf16_t* __restrict__ A,
                                              const int* __restrict__ offsets,
                                              const int* __restrict__ ccol,
                                              const float* __restrict__ cval,
                                              bf16_t* __restrict__ Aout) {
    int n = blockIdx.x;                 // node
    int w = threadIdx.x >> 6;           // batch (4 waves = 4 batches)
    int lane = threadIdx.x & 63;
    int beg = offsets[n], end = offsets[n + 1];
    float a0 = 0.f, a1 = 0.f, a2 = 0.f, a3 = 0.f;
    const size_t bbase = (size_t)w * N_NODES * K_DIM;
    for (int i = beg; i < end; ++i) {
        int c = ccol[i];
        float v = cval[i];
        bf16x4 x = *reinterpret_cast<const bf16x4*>(A + bbase + (size_t)c * K_DIM + lane * 4);
        a0 += v * (float)x[0]; a1 += v * (float)x[1];
        a2 += v * (float)x[2]; a3 += v * (float)x[3];
    }
    bf16x4 o = { (bf16_t)a0, (bf16_t)a1, (bf16_t)a2, (bf16_t)a3 };
    *reinterpret_cast<bf16x4*>(Aout + bbase + (size_t)n * K_DIM + F_DIM + lane * 4) = o;
}

// ---------- fused GEMM: out[m,o] = sum_k A[m,k]*Wt[o,k] + bias[o] ----------
#define BM 128
#define BN 128
#define BK 64

#define GLOAD_LDS16(gptr, lptr)                                                  \
    __builtin_amdgcn_global_load_lds(                                            \
        (const __attribute__((address_space(1))) unsigned int*)(gptr),           \
        (__attribute__((address_space(3))) unsigned int*)(lptr), 16, 0, 0)

__global__ void __launch_bounds__(256) k_gemm(const bf16_t* __restrict__ A,   // [M_ROWS][K_DIM]
                                              const bf16_t* __restrict__ Bt,  // [O_DIM][K_DIM]
                                              const float* __restrict__ bias,
                                              float* __restrict__ out) {      // [M_ROWS][O_DIM]
    __shared__ bf16_t As[BM * BK];   // [128][64] linear (global_load_lds needs linear dest)
    __shared__ bf16_t Bs[BN * BK];

    const int tile_m = (blockIdx.x >> 1) * BM;    // 625 m-tiles
    const int tile_n = (blockIdx.x & 1) * BN;     // 2 n-tiles
    const int tid  = threadIdx.x;
    const int lane = tid & 63;
    const int w    = tid >> 6;
    const int wm   = (w >> 1) * 64;               // wave sub-tile origin
    const int wn   = (w & 1) * 64;

    f32x4 acc[4][4];
#pragma unroll
    for (int i = 0; i < 4; ++i)
#pragma unroll
        for (int j = 0; j < 4; ++j) acc[i][j] = (f32x4){0.f, 0.f, 0.f, 0.f};

    for (int k0 = 0; k0 < K_DIM; k0 += BK) {
        // stage A-tile and B-tile: each is 1024 x 16B chunks; 256 threads x 4 chunks
#pragma unroll
        for (int c = 0; c < 4; ++c) {
            int i = c * 256 + tid;                 // 0..1023
            int row = i >> 3;
            int kc  = (i & 7) << 3;                // bf16 elems
            GLOAD_LDS16(A  + (size_t)(tile_m + row) * K_DIM + k0 + kc, &As[i * 8]);
            GLOAD_LDS16(Bt + (size_t)(tile_n + row) * K_DIM + k0 + kc, &Bs[i * 8]);
        }
        __syncthreads();   // compiler emits vmcnt(0) drain before barrier

#pragma unroll
        for (int ks = 0; ks < 2; ++ks) {
            bf16x8 af[4], bfr[4];
            const int kk = ks * 32 + ((lane >> 4) << 3);
#pragma unroll
            for (int i = 0; i < 4; ++i) {
                af[i]  = *reinterpret_cast<const bf16x8*>(&As[(wm + i * 16 + (lane & 15)) * BK + kk]);
                bfr[i] = *reinterpret_cast<const bf16x8*>(&Bs[(wn + i * 16 + (lane & 15)) * BK + kk]);
            }
#pragma unroll
            for (int i = 0; i < 4; ++i)
#pragma unroll
                for (int j = 0; j < 4; ++j)
                    acc[i][j] = __builtin_amdgcn_mfma_f32_16x16x32_bf16(af[i], bfr[j], acc[i][j], 0, 0, 0);
        }
        __syncthreads();
    }

    // epilogue: C/D layout col=lane&15, row=(lane>>4)*4+r  [verified m89/m91]
#pragma unroll
    for (int j = 0; j < 4; ++j) {
        const int col = tile_n + wn + j * 16 + (lane & 15);
        const float bv = bias[col];
#pragma unroll
        for (int i = 0; i < 4; ++i) {
            const int row0 = tile_m + wm + i * 16 + ((lane >> 4) << 2);
#pragma unroll
            for (int r = 0; r < 4; ++r)
                out[(size_t)(row0 + r) * O_DIM + col] = acc[i][j][r] + bv;
        }
    }
}

extern "C" void kernel_launch(void* const* d_in, const int* in_sizes, int n_in,
                              void* d_out, int out_size, void* d_ws, size_t ws_size,
                              hipStream_t stream) {
    const float* X    = (const float*)d_in[0];
    const int*   rows = (const int*)d_in[1];
    const int*   cols = (const int*)d_in[2];
    const float* vals = (const float*)d_in[3];
    const float* W1   = (const float*)d_in[4];
    const float* W2   = (const float*)d_in[5];
    const float* bias = (const float*)d_in[6];
    float* out = (float*)d_out;

    char* ws = (char*)d_ws;
    size_t off = 0;
    bf16_t* Abuf = (bf16_t*)(ws + off); off += (size_t)M_ROWS * K_DIM * 2;   // 81,920,000 B
    bf16_t* Wt   = (bf16_t*)(ws + off); off += (size_t)O_DIM * K_DIM * 2;    // 262,144 B
    int* deg     = (int*)(ws + off);    off += (size_t)N_NODES * 4;
    int* offsets = (int*)(ws + off);    off += (size_t)(N_NODES + 1) * 4;
    int* cursor  = (int*)(ws + off);    off += (size_t)N_NODES * 4;
    off = (off + 15) & ~(size_t)15;
    int*   ccol  = (int*)(ws + off);    off += (size_t)E_EDGES * 4;
    float* cval  = (float*)(ws + off);  off += (size_t)E_EDGES * 4;

    hipMemsetAsync(deg, 0, (size_t)N_NODES * 4, stream);

    k_convert_x<<<M_ROWS / 4, 256, 0, stream>>>(X, Abuf);          // 20000 blocks
    k_wt<<<K_DIM, O_DIM, 0, stream>>>(W1, W2, Wt);
    k_deg<<<E_EDGES / 256, 256, 0, stream>>>(rows, deg);
    k_scan<<<1, 256, 0, stream>>>(deg, offsets, cursor);
    k_scatter<<<E_EDGES / 256, 256, 0, stream>>>(rows, cols, vals, cursor, ccol, cval);
    k_spmm<<<N_NODES, 256, 0, stream>>>(Abuf, offsets, ccol, cval, Abuf);
    k_gemm<<<(M_ROWS / BM) * (O_DIM / BN), 256, 0, stream>>>(Abuf, Wt, bias, out);
}